// Round 19
// baseline (295.196 us; speedup 1.0000x reference)
//
#include <hip/hip_runtime.h>
#include <hip/hip_fp16.h>
#include <stdint.h>

// MPNN layer (R19 = R18 + T14 async-split in msg_fused: P12 gathers hoisted
// before the MFMA phase so their L3 latency hides under staging+MFMA+Et).
//  h[e] = P1[src] + P2[dst] + Et[e] + b1 ; u = silu(LN(h)) ; Et in LDS only.
//  Interior-run plain stores, boundary runs atomic.
//  agg fused into upd: GEMM1 = x@Wu1a + S@(W2@Wu1b) + cnt*(b2@Wu1b) + bu1

#define N_NODES 100000
#define N_EDGES 800000
#define NODE_DIM 64
#define EDGE_DIM 32
#define HIDDEN 128
#define LN_EPS 1e-5f

#define PH 136   // bf16 tile pitch, 128 data cols
#define PX 72    // P12-GEMM A pitch (64 data cols)
#define PU 200   // upd A-tile pitch (192 data cols)
#define PE 36    // ea A-tile pitch (32 data cols)

#define NB_SCAN ((N_NODES + 1023) / 1024)   // 98
#define SCAT_BLKS 3125
#define SZERO_BLKS 12500   // N*128/4 float4s / 256

typedef __attribute__((ext_vector_type(8))) short short8;
typedef __attribute__((ext_vector_type(4))) float f32x4;

static __device__ __forceinline__ uint16_t f2bf(float f) {
  uint32_t u = __float_as_uint(f);
  return (uint16_t)((u + 0x7FFFu + ((u >> 16) & 1u)) >> 16);
}
static __device__ __forceinline__ float bflo(uint32_t u) {
  return __uint_as_float(u << 16);
}
static __device__ __forceinline__ float bfhi(uint32_t u) {
  return __uint_as_float(u & 0xFFFF0000u);
}
static __device__ __forceinline__ float bfs(uint16_t u) {
  return __uint_as_float(((uint32_t)u) << 16);
}

// ---------------- prepass: hist + pack weights + W2u/qv ----------------

#define PREP_HIST_BLKS 3125
#define PREP_PACK_BLKS 209

__global__ void prep_kernel(const int* __restrict__ ei, int* __restrict__ cnt,
                            const float* __restrict__ W1, uint16_t* __restrict__ Wcatp,
                            uint16_t* __restrict__ W1cb,
                            const float* __restrict__ Wu1, uint16_t* __restrict__ Wu1p,
                            const float* __restrict__ Wu2, uint16_t* __restrict__ Wu2p,
                            const float* __restrict__ W2, const float* __restrict__ b2,
                            float* __restrict__ qv) {
  int b = blockIdx.x;
  if (b < PREP_HIST_BLKS) {
    int e = b * 256 + threadIdx.x;
    if (e < N_EDGES) atomicAdd(&cnt[ei[N_EDGES + e]], 1);
    return;
  }
  int i = (b - PREP_HIST_BLKS) * 256 + threadIdx.x;
  if (i < 16384) {          // Wcat: K=64, C=256  ([W1a | W1b])
    int k = i >> 8, c = i & 255;
    float v = (c < 128) ? W1[k * 128 + c] : W1[(64 + k) * 128 + (c - 128)];
    Wcatp[(((k >> 5) * 256 + c) * 4 + ((k >> 3) & 3)) * 8 + (k & 7)] = f2bf(v);
  } else if (i < 24576) {   // Wu1 rows 0..63 (x-part), C=128
    i -= 16384;
    int k = i >> 7, c = i & 127;
    Wu1p[(((k >> 5) * 128 + c) * 4 + ((k >> 3) & 3)) * 8 + (k & 7)] = f2bf(Wu1[i]);
  } else if (i < 32768) {   // Wu2: K=128, C=64
    i -= 24576;
    int k = i >> 6, c = i & 63;
    Wu2p[(((k >> 5) * 64 + c) * 4 + ((k >> 3) & 3)) * 8 + (k & 7)] = f2bf(Wu2[i]);
  } else if (i < 36864) {   // W1c rows 128..159 of W1 (K=32, C=128) MFMA B-pack
    i -= 32768;
    int k = i >> 7, c = i & 127;
    W1cb[((size_t)(c * 4) + ((k >> 3) & 3)) * 8 + (k & 7)] = f2bf(W1[(128 + k) * 128 + c]);
  } else if (i < 53248) {   // W2u = W2 @ Wu1[64:192] -> Wu1p rows 64..191
    i -= 36864;
    int k = i >> 7, c = i & 127;
    float s = 0.f;
    for (int j = 0; j < 128; ++j) s += W2[k * 128 + j] * Wu1[(64 + j) * 128 + c];
    int kk = 64 + k;
    Wu1p[(((kk >> 5) * 128 + c) * 4 + ((kk >> 3) & 3)) * 8 + (kk & 7)] = f2bf(s);
  } else if (i < 53376) {   // qv = b2 @ Wu1[64:192]
    int c = i - 53248;
    float s = 0.f;
    for (int j = 0; j < 128; ++j) s += b2[j] * Wu1[(64 + j) * 128 + c];
    qv[c] = s;
  }
}

// ---------------- counting sort by dst ----------------

__global__ __launch_bounds__(256) void scan_blk(const int* __restrict__ cnt,
                                                int* __restrict__ offs,
                                                int* __restrict__ bsum) {
  __shared__ int wsum[4];
  int tid = threadIdx.x;
  int base = blockIdx.x * 1024 + tid * 4;
  int v0 = 0, v1 = 0, v2 = 0, v3 = 0;
  if (base < N_NODES) v0 = cnt[base];
  if (base + 1 < N_NODES) v1 = cnt[base + 1];
  if (base + 2 < N_NODES) v2 = cnt[base + 2];
  if (base + 3 < N_NODES) v3 = cnt[base + 3];
  int tsum = v0 + v1 + v2 + v3;
  int lane = tid & 63, wid = tid >> 6;
  int s = tsum;
  #pragma unroll
  for (int d = 1; d < 64; d <<= 1) {
    int t = __shfl_up(s, d);
    if (lane >= d) s += t;
  }
  if (lane == 63) wsum[wid] = s;
  __syncthreads();
  int woff = 0;
  for (int w = 0; w < wid; ++w) woff += wsum[w];
  int excl = woff + s - tsum;
  if (base < N_NODES) {
    int run = excl;
    offs[base] = run; run += v0;
    if (base + 1 < N_NODES) { offs[base + 1] = run; run += v1; }
    if (base + 2 < N_NODES) { offs[base + 2] = run; run += v2; }
    if (base + 3 < N_NODES) { offs[base + 3] = run; run += v3; }
  }
  if (tid == 255) bsum[blockIdx.x] = woff + s;
}

__global__ void scan_top(int* __restrict__ bsum) {
  __shared__ int sh[128];
  int tid = threadIdx.x;
  int v = (tid < NB_SCAN) ? bsum[tid] : 0;
  int orig = v;
  sh[tid] = v;
  __syncthreads();
  for (int d = 1; d < 128; d <<= 1) {
    int t = (tid >= d) ? sh[tid - d] : 0;
    __syncthreads();
    v += t;
    sh[tid] = v;
    __syncthreads();
  }
  if (tid < NB_SCAN) bsum[tid] = v - orig;
}

__global__ void scan_add(const int* __restrict__ offs, const int* __restrict__ bsum,
                         int* __restrict__ cursor) {
  int i = blockIdx.x * 256 + threadIdx.x;
  if (i < N_NODES) cursor[i] = offs[i] + bsum[i >> 10];
}

// scatter + S-zeroing fused in one launch (independent block ranges)
__global__ void scatter_edges(const int* __restrict__ ei, int* __restrict__ cursor,
                              int2* __restrict__ se_s, int* __restrict__ dst_s,
                              float* __restrict__ S) {
  int b = blockIdx.x;
  if (b >= SCAT_BLKS) {
    int i = (b - SCAT_BLKS) * 256 + threadIdx.x;   // float4 index
    float4 z; z.x = 0.f; z.y = 0.f; z.z = 0.f; z.w = 0.f;
    *(float4*)(S + (size_t)i * 4) = z;
    return;
  }
  int e = b * 256 + threadIdx.x;
  if (e < N_EDGES) {
    int s = ei[e], d = ei[N_EDGES + e];
    int p = atomicAdd(&cursor[d], 1);
    se_s[p] = make_int2(s, e);
    dst_s[p] = d;
  }
}

// ---------------- P12 = x @ [W1a|W1b]  (N x 256, bf16) ----------------

__global__ __launch_bounds__(256) void p12_kernel(
    const float* __restrict__ x, const uint16_t* __restrict__ Wcatp,
    uint16_t* __restrict__ P12) {
  __shared__ __align__(16) uint16_t A[64 * PX];
  const int tid = threadIdx.x;
  const int n0 = blockIdx.x * 64;

  #pragma unroll
  for (int it = 0; it < 4; ++it) {
    int u = tid + it * 256;
    int r = u >> 4, q = u & 15;
    int node = min(n0 + r, N_NODES - 1);
    float4 f = *(const float4*)(x + (size_t)node * 64 + q * 4);
    ushort4 o;
    o.x = f2bf(f.x); o.y = f2bf(f.y); o.z = f2bf(f.z); o.w = f2bf(f.w);
    *(ushort4*)(&A[r * PX + q * 4]) = o;
  }
  __syncthreads();

  const int wid = tid >> 6, lane = tid & 63;
  const int lrow = lane & 15, lk = lane >> 4;
  const int r0 = wid * 16;

  f32x4 acc[16] = {};
  const uint16_t* Abase = &A[(r0 + lrow) * PX + lk * 8];
  #pragma unroll
  for (int c = 0; c < 2; ++c) {
    short8 a = *(const short8*)(Abase + c * 32);
    #pragma unroll
    for (int n = 0; n < 16; ++n) {
      short8 b = *(const short8*)(Wcatp + ((size_t)(c * 256 + n * 16 + lrow) * 4 + lk) * 8);
      acc[n] = __builtin_amdgcn_mfma_f32_16x16x32_bf16(a, b, acc[n], 0, 0, 0);
    }
  }

  #pragma unroll
  for (int reg = 0; reg < 4; ++reg) {
    int row = n0 + r0 + lk * 4 + reg;
    if (row < N_NODES) {
      #pragma unroll
      for (int n = 0; n < 16; ++n) {
        P12[(size_t)row * 256 + n * 16 + lrow] = f2bf(acc[n][reg]);
      }
    }
  }
}

// ------- fused msg kernel: Et in LDS, group-mode LN/silu, wave-local reduce.
//         P12 gathers hoisted before the MFMA phase (latency hiding). -------

__global__ __launch_bounds__(256) void msg_fused(
    const int2* __restrict__ se_s, const int* __restrict__ dst_s,
    const float* __restrict__ ea,
    const uint16_t* __restrict__ P12, const uint16_t* __restrict__ W1cb,
    const float* __restrict__ b1, const float* __restrict__ g1,
    const float* __restrict__ be1, float* __restrict__ S) {
  __shared__ __align__(16) uint16_t Ae[64 * PE];   // ea tile (bf16)
  __shared__ __align__(16) uint16_t Hs[64 * PH];   // Et tile -> u tile (bf16)
  __shared__ int sdst[64];

  const int tid = threadIdx.x;
  // bijective XCD swizzle (nwg = 12500 = 8*1562 + 4)
  int bid = blockIdx.x;
  int xcd = bid & 7, idx = bid >> 3;
  int bswz = (xcd < 4 ? xcd * 1563 : 6252 + (xcd - 4) * 1562) + idx;
  const int e0 = bswz * 64;

  if (tid < 64) sdst[tid] = dst_s[e0 + tid];

  const int wid = tid >> 6, lane = tid & 63;
  const int lrow = lane & 15, lk = lane >> 4;
  const int r0 = wid * 16;
  const int g = lk;
  const int c0 = lrow * 8;

  // per-lane constants (issue early; independent of everything else)
  float b1v[8], gv[8], bev[8];
  {
    float4 f0 = *(const float4*)(b1 + c0), f1 = *(const float4*)(b1 + c0 + 4);
    b1v[0]=f0.x; b1v[1]=f0.y; b1v[2]=f0.z; b1v[3]=f0.w;
    b1v[4]=f1.x; b1v[5]=f1.y; b1v[6]=f1.z; b1v[7]=f1.w;
    float4 g0 = *(const float4*)(g1 + c0), g1v = *(const float4*)(g1 + c0 + 4);
    gv[0]=g0.x; gv[1]=g0.y; gv[2]=g0.z; gv[3]=g0.w;
    gv[4]=g1v.x; gv[5]=g1v.y; gv[6]=g1v.z; gv[7]=g1v.w;
    float4 be0 = *(const float4*)(be1 + c0), be1v = *(const float4*)(be1 + c0 + 4);
    bev[0]=be0.x; bev[1]=be0.y; bev[2]=be0.z; bev[3]=be0.w;
    bev[4]=be1v.x; bev[5]=be1v.y; bev[6]=be1v.z; bev[7]=be1v.w;
  }

  // stage ea[eid] -> Ae (4 threads/edge, f32 -> bf16)
  {
    int pl = tid >> 2, q = tid & 3;
    int eid = se_s[e0 + pl].y;
    const float* er = ea + (size_t)eid * 32 + q * 8;
    float4 f0 = *(const float4*)(er);
    float4 f1 = *(const float4*)(er + 4);
    ushort4 o0, o1;
    o0.x = f2bf(f0.x); o0.y = f2bf(f0.y); o0.z = f2bf(f0.z); o0.w = f2bf(f0.w);
    o1.x = f2bf(f1.x); o1.y = f2bf(f1.y); o1.z = f2bf(f1.z); o1.w = f2bf(f1.w);
    *(ushort4*)(&Ae[pl * PE + q * 8]) = o0;
    *(ushort4*)(&Ae[pl * PE + q * 8 + 4]) = o1;
  }
  __syncthreads();

  // --- T14 async-split: issue ALL group-mode P12 gathers NOW, consume after
  //     the MFMA/Et phase (latency hides under staging reads + 8 MFMA + Et).
  uint4 up1[4], up2[4];
  #pragma unroll
  for (int it = 0; it < 4; ++it) {
    int er_ = r0 + it * 4 + g;
    int p = e0 + er_;
    int src = se_s[p].x;
    int d = sdst[er_];
    up1[it] = *(const uint4*)(P12 + (size_t)src * 256 + c0);
    up2[it] = *(const uint4*)(P12 + (size_t)d * 256 + 128 + c0);
  }

  // Et (16 edges x 128) = Ae-strip @ W1c : 8 MFMA per wave
  f32x4 acc[8] = {};
  short8 a = *(const short8*)(&Ae[(r0 + lrow) * PE + lk * 8]);
  #pragma unroll
  for (int n = 0; n < 8; ++n) {
    short8 b = *(const short8*)(W1cb + ((size_t)((n * 16 + lrow) * 4) + lk) * 8);
    acc[n] = __builtin_amdgcn_mfma_f32_16x16x32_bf16(a, b, acc[n], 0, 0, 0);
  }
  // write Et to this wave's LDS strip (wave-private; in-wave DS ordering)
  #pragma unroll
  for (int reg = 0; reg < 4; ++reg) {
    uint16_t* hrow = &Hs[(r0 + lk * 4 + reg) * PH];
    #pragma unroll
    for (int n = 0; n < 8; ++n) {
      hrow[n * 16 + lrow] = f2bf(acc[n][reg]);
    }
  }

  // group-mode: 16-lane group g handles edge r0 + it*4 + g, 8 cols/lane
  #pragma unroll
  for (int it = 0; it < 4; ++it) {
    int er_ = r0 + it * 4 + g;
    uint4 p1 = up1[it];
    uint4 p2 = up2[it];
    uint4 et = *(const uint4*)(&Hs[er_ * PH + c0]);
    float h[8];
    h[0] = b1v[0] + bflo(p1.x) + bflo(p2.x) + bflo(et.x);
    h[1] = b1v[1] + bfhi(p1.x) + bfhi(p2.x) + bfhi(et.x);
    h[2] = b1v[2] + bflo(p1.y) + bflo(p2.y) + bflo(et.y);
    h[3] = b1v[3] + bfhi(p1.y) + bfhi(p2.y) + bfhi(et.y);
    h[4] = b1v[4] + bflo(p1.z) + bflo(p2.z) + bflo(et.z);
    h[5] = b1v[5] + bfhi(p1.z) + bfhi(p2.z) + bfhi(et.z);
    h[6] = b1v[6] + bflo(p1.w) + bflo(p2.w) + bflo(et.w);
    h[7] = b1v[7] + bfhi(p1.w) + bfhi(p2.w) + bfhi(et.w);

    float s = 0.f, ss = 0.f;
    #pragma unroll
    for (int j = 0; j < 8; ++j) { s += h[j]; ss += h[j] * h[j]; }
    #pragma unroll
    for (int m = 1; m <= 8; m <<= 1) {
      s += __shfl_xor(s, m);
      ss += __shfl_xor(ss, m);
    }
    float mu = s * (1.f / 128.f);
    float vr = ss * (1.f / 128.f) - mu * mu + LN_EPS;
    float rstd;
    asm("v_rsq_f32 %0, %1" : "=v"(rstd) : "v"(vr));
    ushort4 u0, u1;
    uint16_t uu[8];
    #pragma unroll
    for (int j = 0; j < 8; ++j) {
      float xv = (h[j] - mu) * rstd * gv[j] + bev[j];
      float tv = xv * -1.44269504f;
      float ev, rv;
      asm("v_exp_f32 %0, %1" : "=v"(ev) : "v"(tv));
      float dv = 1.f + ev;
      asm("v_rcp_f32 %0, %1" : "=v"(rv) : "v"(dv));
      uu[j] = f2bf(xv * rv);
    }
    u0.x = uu[0]; u0.y = uu[1]; u0.z = uu[2]; u0.w = uu[3];
    u1.x = uu[4]; u1.y = uu[5]; u1.z = uu[6]; u1.w = uu[7];
    *(ushort4*)(&Hs[er_ * PH + c0]) = u0;       // overwrite Et row with u
    *(ushort4*)(&Hs[er_ * PH + c0 + 4]) = u1;
  }

  // wave-local segmented reduction over this wave's 16 sorted rows.
  // Interior runs -> sole writer -> plain store; boundary runs -> atomics.
  {
    int c = lane * 2;
    int cur = sdst[r0];
    int rstart = 0;                        // wave-uniform
    ushort2 o = *(const ushort2*)&Hs[r0 * PH + c];
    float run0 = bfs(o.x), run1 = bfs(o.y);
    #pragma unroll
    for (int i = 1; i < 16; ++i) {
      int r = r0 + i;
      int d = sdst[r];                     // uniform across wave
      ushort2 t = *(const ushort2*)&Hs[r * PH + c];
      float v0 = bfs(t.x), v1 = bfs(t.y);
      if (d != cur) {
        if (rstart > 0) {                  // interior: sole writer
          float2 ov; ov.x = run0; ov.y = run1;
          *(float2*)(S + (size_t)cur * HIDDEN + c) = ov;
        } else {
          atomicAdd(S + (size_t)cur * HIDDEN + c,     run0);
          atomicAdd(S + (size_t)cur * HIDDEN + c + 1, run1);
        }
        run0 = v0; run1 = v1; cur = d; rstart = i;
      } else {
        run0 += v0; run1 += v1;
      }
    }
    atomicAdd(S + (size_t)cur * HIDDEN + c,     run0);   // last: may continue
    atomicAdd(S + (size_t)cur * HIDDEN + c + 1, run1);
  }
}

// ------- update: out = x + MLP2(silu(LN(x@Wu1a + S@W2u + cnt*q + bu1))) -------

__global__ __launch_bounds__(256) void upd_kernel(
    const float* __restrict__ x, const float* __restrict__ S,
    const int* __restrict__ cnt, const float* __restrict__ qv,
    const uint16_t* __restrict__ Wu1p, const float* __restrict__ b1,
    const float* __restrict__ g1, const float* __restrict__ be1,
    const uint16_t* __restrict__ Wu2p, const float* __restrict__ b2,
    float* __restrict__ out) {
  __shared__ __align__(16) uint16_t A[64 * PU];
  __shared__ float sb1[128], sg[128], sbe[128], sb2[64], sq[128], scnt[64];

  const int tid = threadIdx.x;
  const int n0 = blockIdx.x * 64;

  if (tid < 128) { sb1[tid] = b1[tid]; sg[tid] = g1[tid]; }
  else { sbe[tid - 128] = be1[tid - 128]; sq[tid - 128] = qv[tid - 128]; }
  if (tid < 64) {
    sb2[tid] = b2[tid];
    scnt[tid] = (float)cnt[min(n0 + tid, N_NODES - 1)];
  }

  #pragma unroll
  for (int it = 0; it < 4; ++it) {
    int u = tid + it * 256;
    int r = u >> 4, q = u & 15;
    int node = min(n0 + r, N_NODES - 1);
    float4 f = *(const float4*)(x + (size_t)node * 64 + q * 4);
    ushort4 o;
    o.x = f2bf(f.x); o.y = f2bf(f.y); o.z = f2bf(f.z); o.w = f2bf(f.w);
    *(ushort4*)(&A[r * PU + q * 4]) = o;
  }
  #pragma unroll
  for (int it = 0; it < 8; ++it) {
    int u = tid + it * 256;
    int r = u >> 5, q = u & 31;
    int node = min(n0 + r, N_NODES - 1);
    float4 f = *(const float4*)(S + (size_t)node * 128 + q * 4);
    ushort4 o;
    o.x = f2bf(f.x); o.y = f2bf(f.y); o.z = f2bf(f.z); o.w = f2bf(f.w);
    *(ushort4*)(&A[r * PU + 64 + q * 4]) = o;
  }
  __syncthreads();

  const int wid = tid >> 6, lane = tid & 63;
  const int lrow = lane & 15, lk = lane >> 4;
  const int r0 = wid * 16;

  // GEMM1: (64x192) @ (192x128)  [weight rows 64..191 = W2u]
  f32x4 acc[8] = {};
  const uint16_t* Abase = &A[(r0 + lrow) * PU + lk * 8];
  #pragma unroll
  for (int c = 0; c < 6; ++c) {
    short8 a = *(const short8*)(Abase + c * 32);
    #pragma unroll
    for (int n = 0; n < 8; ++n) {
      short8 b = *(const short8*)(Wu1p + ((size_t)((c * 128) + (n * 16 + lrow)) * 4 + lk) * 8);
      acc[n] = __builtin_amdgcn_mfma_f32_16x16x32_bf16(a, b, acc[n], 0, 0, 0);
    }
  }

  // bias + cnt*q + LN + SiLU -> Hs (strip overlay on A)
  uint16_t* strip = &A[r0 * PU];
  #pragma unroll
  for (int reg = 0; reg < 4; ++reg) {
    float cf = scnt[r0 + lk * 4 + reg];
    float v[8];
    float s = 0.f, ss = 0.f;
    #pragma unroll
    for (int n = 0; n < 8; ++n) {
      int col = n * 16 + lrow;
      v[n] = acc[n][reg] + sb1[col] + cf * sq[col];
      s += v[n]; ss += v[n] * v[n];
    }
    #pragma unroll
    for (int m = 1; m <= 8; m <<= 1) {
      s += __shfl_xor(s, m);
      ss += __shfl_xor(ss, m);
    }
    float mu = s * (1.f / 128.f);
    float rstd = rsqrtf(ss * (1.f / 128.f) - mu * mu + LN_EPS);
    uint16_t* hrow = strip + (lk * 4 + reg) * PH;
    #pragma unroll
    for (int n = 0; n < 8; ++n) {
      int col = n * 16 + lrow;
      float h = (v[n] - mu) * rstd * sg[col] + sbe[col];
      h = h / (1.f + __expf(-h));
      hrow[col] = f2bf(h);
    }
  }

  // GEMM2: (64x128) @ (128x64)
  f32x4 acc2[4] = {};
  const uint16_t* Hbase = strip + lrow * PH + lk * 8;
  #pragma unroll
  for (int c = 0; c < 4; ++c) {
    short8 a = *(const short8*)(Hbase + c * 32);
    #pragma unroll
    for (int n = 0; n < 4; ++n) {
      short8 b = *(const short8*)(Wu2p + ((size_t)((c * 64) + (n * 16 + lrow)) * 4 + lk) * 8);
      acc2[n] = __builtin_amdgcn_mfma_f32_16x16x32_bf16(a, b, acc2[n], 0, 0, 0);
    }
  }

  // residual + bias + store f32
  #pragma unroll
  for (int reg = 0; reg < 4; ++reg) {
    int node = n0 + r0 + lk * 4 + reg;
    if (node < N_NODES) {
      #pragma unroll
      for (int n = 0; n < 4; ++n) {
        int col = n * 16 + lrow;
        out[(size_t)node * 64 + col] =
            x[(size_t)node * 64 + col] + acc2[n][reg] + sb2[col];
      }
    }
  }
}

extern "C" void kernel_launch(void* const* d_in, const int* in_sizes, int n_in,
                              void* d_out, int out_size, void* d_ws, size_t ws_size,
                              hipStream_t stream) {
  const float* x   = (const float*)d_in[0];
  const int*   ei  = (const int*)d_in[1];
  const float* ea  = (const float*)d_in[2];
  const float* W1  = (const float*)d_in[3];
  const float* b1  = (const float*)d_in[4];
  const float* g1  = (const float*)d_in[5];
  const float* be1 = (const float*)d_in[6];
  const float* W2  = (const float*)d_in[7];
  const float* b2  = (const float*)d_in[8];
  const float* Wu1 = (const float*)d_in[9];
  const float* bu1 = (const float*)d_in[10];
  const float* gu  = (const float*)d_in[11];
  const float* beu = (const float*)d_in[12];
  const float* Wu2 = (const float*)d_in[13];
  const float* bu2 = (const float*)d_in[14];
  float* out = (float*)d_out;

  char* ws = (char*)d_ws;
  float*    S      = (float*)ws;                        // 51,200,000
  uint16_t* P12    = (uint16_t*)(ws + 51200000);        // 51,200,000
  uint16_t* Wcatp  = (uint16_t*)(ws + 102400000);       // 32,768
  uint16_t* Wu1p   = (uint16_t*)(ws + 102432768);       // 49,152
  uint16_t* Wu2p   = (uint16_t*)(ws + 102481920);       // 16,384
  uint16_t* W1cb   = (uint16_t*)(ws + 102498304);       // 8,192
  float*    qv     = (float*)(ws + 102506496);          // 512
  int*      cnt    = (int*)(ws + 102507008);            // 400,000
  int*      offs   = (int*)(ws + 102907008);            // 400,000
  int*      cursor = (int*)(ws + 103307008);            // 400,000
  int*      bsum   = (int*)(ws + 103707008);            // 512
  int2*     se_s   = (int2*)(ws + 103707520);           // 6,400,000
  int*      dst_s  = (int*)(ws + 110107520);            // 3,200,000 (end ~113.3 MB)

  (void)hipMemsetAsync(cnt, 0, (size_t)N_NODES * 4, stream);

  prep_kernel<<<PREP_HIST_BLKS + PREP_PACK_BLKS, 256, 0, stream>>>(
      ei, cnt, W1, Wcatp, W1cb, Wu1, Wu1p, Wu2, Wu2p, W2, b2, qv);

  scan_blk<<<NB_SCAN, 256, 0, stream>>>(cnt, offs, bsum);
  scan_top<<<1, 128, 0, stream>>>(bsum);
  scan_add<<<(N_NODES + 255) / 256, 256, 0, stream>>>(offs, bsum, cursor);
  scatter_edges<<<SCAT_BLKS + SZERO_BLKS, 256, 0, stream>>>(ei, cursor, se_s, dst_s, S);

  p12_kernel<<<(N_NODES + 63) / 64, 256, 0, stream>>>(x, Wcatp, P12);

  msg_fused<<<N_EDGES / 64, 256, 0, stream>>>(se_s, dst_s, ea, P12,
                                              W1cb, b1, g1, be1, S);

  upd_kernel<<<(N_NODES + 63) / 64, 256, 0, stream>>>(x, S, cnt, qv,
                                                      Wu1p, bu1, gu, beu, Wu2p, bu2, out);
}

// Round 20
// 282.877 us; speedup vs baseline: 1.0435x; 1.0435x over previous
//
#include <hip/hip_runtime.h>
#include <hip/hip_fp16.h>
#include <stdint.h>

// MPNN layer (R20 = R18 restore, best validated config @ 288.8us).
//  R19's gather-hoist regressed (146->155us: compiler already hid the
//  latency; forced live registers hurt scheduling) -> reverted.
//  h[e] = P1[src] + P2[dst] + Et[e] + b1 ; u = silu(LN(h)) ; Et in LDS only.
//  Interior-run plain stores, boundary runs atomic.
//  agg fused into upd: GEMM1 = x@Wu1a + S@(W2@Wu1b) + cnt*(b2@Wu1b) + bu1

#define N_NODES 100000
#define N_EDGES 800000
#define NODE_DIM 64
#define EDGE_DIM 32
#define HIDDEN 128
#define LN_EPS 1e-5f

#define PH 136   // bf16 tile pitch, 128 data cols
#define PX 72    // P12-GEMM A pitch (64 data cols)
#define PU 200   // upd A-tile pitch (192 data cols)
#define PE 36    // ea A-tile pitch (32 data cols)

#define NB_SCAN ((N_NODES + 1023) / 1024)   // 98
#define SCAT_BLKS 3125
#define SZERO_BLKS 12500   // N*128/4 float4s / 256

typedef __attribute__((ext_vector_type(8))) short short8;
typedef __attribute__((ext_vector_type(4))) float f32x4;

static __device__ __forceinline__ uint16_t f2bf(float f) {
  uint32_t u = __float_as_uint(f);
  return (uint16_t)((u + 0x7FFFu + ((u >> 16) & 1u)) >> 16);
}
static __device__ __forceinline__ float bflo(uint32_t u) {
  return __uint_as_float(u << 16);
}
static __device__ __forceinline__ float bfhi(uint32_t u) {
  return __uint_as_float(u & 0xFFFF0000u);
}
static __device__ __forceinline__ float bfs(uint16_t u) {
  return __uint_as_float(((uint32_t)u) << 16);
}

// ---------------- prepass: hist + pack weights + W2u/qv ----------------

#define PREP_HIST_BLKS 3125
#define PREP_PACK_BLKS 209

__global__ void prep_kernel(const int* __restrict__ ei, int* __restrict__ cnt,
                            const float* __restrict__ W1, uint16_t* __restrict__ Wcatp,
                            uint16_t* __restrict__ W1cb,
                            const float* __restrict__ Wu1, uint16_t* __restrict__ Wu1p,
                            const float* __restrict__ Wu2, uint16_t* __restrict__ Wu2p,
                            const float* __restrict__ W2, const float* __restrict__ b2,
                            float* __restrict__ qv) {
  int b = blockIdx.x;
  if (b < PREP_HIST_BLKS) {
    int e = b * 256 + threadIdx.x;
    if (e < N_EDGES) atomicAdd(&cnt[ei[N_EDGES + e]], 1);
    return;
  }
  int i = (b - PREP_HIST_BLKS) * 256 + threadIdx.x;
  if (i < 16384) {          // Wcat: K=64, C=256  ([W1a | W1b])
    int k = i >> 8, c = i & 255;
    float v = (c < 128) ? W1[k * 128 + c] : W1[(64 + k) * 128 + (c - 128)];
    Wcatp[(((k >> 5) * 256 + c) * 4 + ((k >> 3) & 3)) * 8 + (k & 7)] = f2bf(v);
  } else if (i < 24576) {   // Wu1 rows 0..63 (x-part), C=128
    i -= 16384;
    int k = i >> 7, c = i & 127;
    Wu1p[(((k >> 5) * 128 + c) * 4 + ((k >> 3) & 3)) * 8 + (k & 7)] = f2bf(Wu1[i]);
  } else if (i < 32768) {   // Wu2: K=128, C=64
    i -= 24576;
    int k = i >> 6, c = i & 63;
    Wu2p[(((k >> 5) * 64 + c) * 4 + ((k >> 3) & 3)) * 8 + (k & 7)] = f2bf(Wu2[i]);
  } else if (i < 36864) {   // W1c rows 128..159 of W1 (K=32, C=128) MFMA B-pack
    i -= 32768;
    int k = i >> 7, c = i & 127;
    W1cb[((size_t)(c * 4) + ((k >> 3) & 3)) * 8 + (k & 7)] = f2bf(W1[(128 + k) * 128 + c]);
  } else if (i < 53248) {   // W2u = W2 @ Wu1[64:192] -> Wu1p rows 64..191
    i -= 36864;
    int k = i >> 7, c = i & 127;
    float s = 0.f;
    for (int j = 0; j < 128; ++j) s += W2[k * 128 + j] * Wu1[(64 + j) * 128 + c];
    int kk = 64 + k;
    Wu1p[(((kk >> 5) * 128 + c) * 4 + ((kk >> 3) & 3)) * 8 + (kk & 7)] = f2bf(s);
  } else if (i < 53376) {   // qv = b2 @ Wu1[64:192]
    int c = i - 53248;
    float s = 0.f;
    for (int j = 0; j < 128; ++j) s += b2[j] * Wu1[(64 + j) * 128 + c];
    qv[c] = s;
  }
}

// ---------------- counting sort by dst ----------------

__global__ __launch_bounds__(256) void scan_blk(const int* __restrict__ cnt,
                                                int* __restrict__ offs,
                                                int* __restrict__ bsum) {
  __shared__ int wsum[4];
  int tid = threadIdx.x;
  int base = blockIdx.x * 1024 + tid * 4;
  int v0 = 0, v1 = 0, v2 = 0, v3 = 0;
  if (base < N_NODES) v0 = cnt[base];
  if (base + 1 < N_NODES) v1 = cnt[base + 1];
  if (base + 2 < N_NODES) v2 = cnt[base + 2];
  if (base + 3 < N_NODES) v3 = cnt[base + 3];
  int tsum = v0 + v1 + v2 + v3;
  int lane = tid & 63, wid = tid >> 6;
  int s = tsum;
  #pragma unroll
  for (int d = 1; d < 64; d <<= 1) {
    int t = __shfl_up(s, d);
    if (lane >= d) s += t;
  }
  if (lane == 63) wsum[wid] = s;
  __syncthreads();
  int woff = 0;
  for (int w = 0; w < wid; ++w) woff += wsum[w];
  int excl = woff + s - tsum;
  if (base < N_NODES) {
    int run = excl;
    offs[base] = run; run += v0;
    if (base + 1 < N_NODES) { offs[base + 1] = run; run += v1; }
    if (base + 2 < N_NODES) { offs[base + 2] = run; run += v2; }
    if (base + 3 < N_NODES) { offs[base + 3] = run; run += v3; }
  }
  if (tid == 255) bsum[blockIdx.x] = woff + s;
}

__global__ void scan_top(int* __restrict__ bsum) {
  __shared__ int sh[128];
  int tid = threadIdx.x;
  int v = (tid < NB_SCAN) ? bsum[tid] : 0;
  int orig = v;
  sh[tid] = v;
  __syncthreads();
  for (int d = 1; d < 128; d <<= 1) {
    int t = (tid >= d) ? sh[tid - d] : 0;
    __syncthreads();
    v += t;
    sh[tid] = v;
    __syncthreads();
  }
  if (tid < NB_SCAN) bsum[tid] = v - orig;
}

__global__ void scan_add(const int* __restrict__ offs, const int* __restrict__ bsum,
                         int* __restrict__ cursor) {
  int i = blockIdx.x * 256 + threadIdx.x;
  if (i < N_NODES) cursor[i] = offs[i] + bsum[i >> 10];
}

// scatter + S-zeroing fused in one launch (independent block ranges)
__global__ void scatter_edges(const int* __restrict__ ei, int* __restrict__ cursor,
                              int2* __restrict__ se_s, int* __restrict__ dst_s,
                              float* __restrict__ S) {
  int b = blockIdx.x;
  if (b >= SCAT_BLKS) {
    int i = (b - SCAT_BLKS) * 256 + threadIdx.x;   // float4 index
    float4 z; z.x = 0.f; z.y = 0.f; z.z = 0.f; z.w = 0.f;
    *(float4*)(S + (size_t)i * 4) = z;
    return;
  }
  int e = b * 256 + threadIdx.x;
  if (e < N_EDGES) {
    int s = ei[e], d = ei[N_EDGES + e];
    int p = atomicAdd(&cursor[d], 1);
    se_s[p] = make_int2(s, e);
    dst_s[p] = d;
  }
}

// ---------------- P12 = x @ [W1a|W1b]  (N x 256, bf16) ----------------

__global__ __launch_bounds__(256) void p12_kernel(
    const float* __restrict__ x, const uint16_t* __restrict__ Wcatp,
    uint16_t* __restrict__ P12) {
  __shared__ __align__(16) uint16_t A[64 * PX];
  const int tid = threadIdx.x;
  const int n0 = blockIdx.x * 64;

  #pragma unroll
  for (int it = 0; it < 4; ++it) {
    int u = tid + it * 256;
    int r = u >> 4, q = u & 15;
    int node = min(n0 + r, N_NODES - 1);
    float4 f = *(const float4*)(x + (size_t)node * 64 + q * 4);
    ushort4 o;
    o.x = f2bf(f.x); o.y = f2bf(f.y); o.z = f2bf(f.z); o.w = f2bf(f.w);
    *(ushort4*)(&A[r * PX + q * 4]) = o;
  }
  __syncthreads();

  const int wid = tid >> 6, lane = tid & 63;
  const int lrow = lane & 15, lk = lane >> 4;
  const int r0 = wid * 16;

  f32x4 acc[16] = {};
  const uint16_t* Abase = &A[(r0 + lrow) * PX + lk * 8];
  #pragma unroll
  for (int c = 0; c < 2; ++c) {
    short8 a = *(const short8*)(Abase + c * 32);
    #pragma unroll
    for (int n = 0; n < 16; ++n) {
      short8 b = *(const short8*)(Wcatp + ((size_t)(c * 256 + n * 16 + lrow) * 4 + lk) * 8);
      acc[n] = __builtin_amdgcn_mfma_f32_16x16x32_bf16(a, b, acc[n], 0, 0, 0);
    }
  }

  #pragma unroll
  for (int reg = 0; reg < 4; ++reg) {
    int row = n0 + r0 + lk * 4 + reg;
    if (row < N_NODES) {
      #pragma unroll
      for (int n = 0; n < 16; ++n) {
        P12[(size_t)row * 256 + n * 16 + lrow] = f2bf(acc[n][reg]);
      }
    }
  }
}

// ------- fused msg kernel: Et in LDS, group-mode LN/silu, wave-local reduce -------

__global__ __launch_bounds__(256) void msg_fused(
    const int2* __restrict__ se_s, const int* __restrict__ dst_s,
    const float* __restrict__ ea,
    const uint16_t* __restrict__ P12, const uint16_t* __restrict__ W1cb,
    const float* __restrict__ b1, const float* __restrict__ g1,
    const float* __restrict__ be1, float* __restrict__ S) {
  __shared__ __align__(16) uint16_t Ae[64 * PE];   // ea tile (bf16)
  __shared__ __align__(16) uint16_t Hs[64 * PH];   // Et tile -> u tile (bf16)
  __shared__ int sdst[64];

  const int tid = threadIdx.x;
  // bijective XCD swizzle (nwg = 12500 = 8*1562 + 4)
  int bid = blockIdx.x;
  int xcd = bid & 7, idx = bid >> 3;
  int bswz = (xcd < 4 ? xcd * 1563 : 6252 + (xcd - 4) * 1562) + idx;
  const int e0 = bswz * 64;

  if (tid < 64) sdst[tid] = dst_s[e0 + tid];

  // stage ea[eid] -> Ae (4 threads/edge, f32 -> bf16)
  {
    int pl = tid >> 2, q = tid & 3;
    int eid = se_s[e0 + pl].y;
    const float* er = ea + (size_t)eid * 32 + q * 8;
    float4 f0 = *(const float4*)(er);
    float4 f1 = *(const float4*)(er + 4);
    ushort4 o0, o1;
    o0.x = f2bf(f0.x); o0.y = f2bf(f0.y); o0.z = f2bf(f0.z); o0.w = f2bf(f0.w);
    o1.x = f2bf(f1.x); o1.y = f2bf(f1.y); o1.z = f2bf(f1.z); o1.w = f2bf(f1.w);
    *(ushort4*)(&Ae[pl * PE + q * 8]) = o0;
    *(ushort4*)(&Ae[pl * PE + q * 8 + 4]) = o1;
  }
  __syncthreads();

  const int wid = tid >> 6, lane = tid & 63;
  const int lrow = lane & 15, lk = lane >> 4;
  const int r0 = wid * 16;

  // Et (16 edges x 128) = Ae-strip @ W1c : 8 MFMA per wave
  f32x4 acc[8] = {};
  short8 a = *(const short8*)(&Ae[(r0 + lrow) * PE + lk * 8]);
  #pragma unroll
  for (int n = 0; n < 8; ++n) {
    short8 b = *(const short8*)(W1cb + ((size_t)((n * 16 + lrow) * 4) + lk) * 8);
    acc[n] = __builtin_amdgcn_mfma_f32_16x16x32_bf16(a, b, acc[n], 0, 0, 0);
  }
  // write Et to this wave's LDS strip (wave-private; in-wave DS ordering)
  #pragma unroll
  for (int reg = 0; reg < 4; ++reg) {
    uint16_t* hrow = &Hs[(r0 + lk * 4 + reg) * PH];
    #pragma unroll
    for (int n = 0; n < 8; ++n) {
      hrow[n * 16 + lrow] = f2bf(acc[n][reg]);
    }
  }

  // group-mode: 16-lane group g handles edge r0 + it*4 + g, 8 cols/lane
  const int g = lk;
  const int c0 = lrow * 8;
  float b1v[8], gv[8], bev[8];
  {
    float4 f0 = *(const float4*)(b1 + c0), f1 = *(const float4*)(b1 + c0 + 4);
    b1v[0]=f0.x; b1v[1]=f0.y; b1v[2]=f0.z; b1v[3]=f0.w;
    b1v[4]=f1.x; b1v[5]=f1.y; b1v[6]=f1.z; b1v[7]=f1.w;
    float4 g0 = *(const float4*)(g1 + c0), g1v = *(const float4*)(g1 + c0 + 4);
    gv[0]=g0.x; gv[1]=g0.y; gv[2]=g0.z; gv[3]=g0.w;
    gv[4]=g1v.x; gv[5]=g1v.y; gv[6]=g1v.z; gv[7]=g1v.w;
    float4 be0 = *(const float4*)(be1 + c0), be1v = *(const float4*)(be1 + c0 + 4);
    bev[0]=be0.x; bev[1]=be0.y; bev[2]=be0.z; bev[3]=be0.w;
    bev[4]=be1v.x; bev[5]=be1v.y; bev[6]=be1v.z; bev[7]=be1v.w;
  }

  #pragma unroll
  for (int it = 0; it < 4; ++it) {
    int er_ = r0 + it * 4 + g;           // edge row in block (this wave's strip)
    int p = e0 + er_;
    int src = se_s[p].x;
    int d = sdst[er_];
    uint4 p1 = *(const uint4*)(P12 + (size_t)src * 256 + c0);
    uint4 p2 = *(const uint4*)(P12 + (size_t)d * 256 + 128 + c0);
    uint4 et = *(const uint4*)(&Hs[er_ * PH + c0]);
    float h[8];
    h[0] = b1v[0] + bflo(p1.x) + bflo(p2.x) + bflo(et.x);
    h[1] = b1v[1] + bfhi(p1.x) + bfhi(p2.x) + bfhi(et.x);
    h[2] = b1v[2] + bflo(p1.y) + bflo(p2.y) + bflo(et.y);
    h[3] = b1v[3] + bfhi(p1.y) + bfhi(p2.y) + bfhi(et.y);
    h[4] = b1v[4] + bflo(p1.z) + bflo(p2.z) + bflo(et.z);
    h[5] = b1v[5] + bfhi(p1.z) + bfhi(p2.z) + bfhi(et.z);
    h[6] = b1v[6] + bflo(p1.w) + bflo(p2.w) + bflo(et.w);
    h[7] = b1v[7] + bfhi(p1.w) + bfhi(p2.w) + bfhi(et.w);

    float s = 0.f, ss = 0.f;
    #pragma unroll
    for (int j = 0; j < 8; ++j) { s += h[j]; ss += h[j] * h[j]; }
    #pragma unroll
    for (int m = 1; m <= 8; m <<= 1) {
      s += __shfl_xor(s, m);
      ss += __shfl_xor(ss, m);
    }
    float mu = s * (1.f / 128.f);
    float vr = ss * (1.f / 128.f) - mu * mu + LN_EPS;
    float rstd;
    asm("v_rsq_f32 %0, %1" : "=v"(rstd) : "v"(vr));
    ushort4 u0, u1;
    uint16_t uu[8];
    #pragma unroll
    for (int j = 0; j < 8; ++j) {
      float xv = (h[j] - mu) * rstd * gv[j] + bev[j];
      float tv = xv * -1.44269504f;
      float ev, rv;
      asm("v_exp_f32 %0, %1" : "=v"(ev) : "v"(tv));
      float dv = 1.f + ev;
      asm("v_rcp_f32 %0, %1" : "=v"(rv) : "v"(dv));
      uu[j] = f2bf(xv * rv);
    }
    u0.x = uu[0]; u0.y = uu[1]; u0.z = uu[2]; u0.w = uu[3];
    u1.x = uu[4]; u1.y = uu[5]; u1.z = uu[6]; u1.w = uu[7];
    *(ushort4*)(&Hs[er_ * PH + c0]) = u0;       // overwrite Et row with u
    *(ushort4*)(&Hs[er_ * PH + c0 + 4]) = u1;
  }

  // wave-local segmented reduction over this wave's 16 sorted rows.
  // Interior runs -> sole writer -> plain store; boundary runs -> atomics.
  {
    int c = lane * 2;
    int cur = sdst[r0];
    int rstart = 0;                        // wave-uniform
    ushort2 o = *(const ushort2*)&Hs[r0 * PH + c];
    float run0 = bfs(o.x), run1 = bfs(o.y);
    #pragma unroll
    for (int i = 1; i < 16; ++i) {
      int r = r0 + i;
      int d = sdst[r];                     // uniform across wave
      ushort2 t = *(const ushort2*)&Hs[r * PH + c];
      float v0 = bfs(t.x), v1 = bfs(t.y);
      if (d != cur) {
        if (rstart > 0) {                  // interior: sole writer
          float2 ov; ov.x = run0; ov.y = run1;
          *(float2*)(S + (size_t)cur * HIDDEN + c) = ov;
        } else {
          atomicAdd(S + (size_t)cur * HIDDEN + c,     run0);
          atomicAdd(S + (size_t)cur * HIDDEN + c + 1, run1);
        }
        run0 = v0; run1 = v1; cur = d; rstart = i;
      } else {
        run0 += v0; run1 += v1;
      }
    }
    atomicAdd(S + (size_t)cur * HIDDEN + c,     run0);   // last: may continue
    atomicAdd(S + (size_t)cur * HIDDEN + c + 1, run1);
  }
}

// ------- update: out = x + MLP2(silu(LN(x@Wu1a + S@W2u + cnt*q + bu1))) -------

__global__ __launch_bounds__(256) void upd_kernel(
    const float* __restrict__ x, const float* __restrict__ S,
    const int* __restrict__ cnt, const float* __restrict__ qv,
    const uint16_t* __restrict__ Wu1p, const float* __restrict__ b1,
    const float* __restrict__ g1, const float* __restrict__ be1,
    const uint16_t* __restrict__ Wu2p, const float* __restrict__ b2,
    float* __restrict__ out) {
  __shared__ __align__(16) uint16_t A[64 * PU];
  __shared__ float sb1[128], sg[128], sbe[128], sb2[64], sq[128], scnt[64];

  const int tid = threadIdx.x;
  const int n0 = blockIdx.x * 64;

  if (tid < 128) { sb1[tid] = b1[tid]; sg[tid] = g1[tid]; }
  else { sbe[tid - 128] = be1[tid - 128]; sq[tid - 128] = qv[tid - 128]; }
  if (tid < 64) {
    sb2[tid] = b2[tid];
    scnt[tid] = (float)cnt[min(n0 + tid, N_NODES - 1)];
  }

  #pragma unroll
  for (int it = 0; it < 4; ++it) {
    int u = tid + it * 256;
    int r = u >> 4, q = u & 15;
    int node = min(n0 + r, N_NODES - 1);
    float4 f = *(const float4*)(x + (size_t)node * 64 + q * 4);
    ushort4 o;
    o.x = f2bf(f.x); o.y = f2bf(f.y); o.z = f2bf(f.z); o.w = f2bf(f.w);
    *(ushort4*)(&A[r * PU + q * 4]) = o;
  }
  #pragma unroll
  for (int it = 0; it < 8; ++it) {
    int u = tid + it * 256;
    int r = u >> 5, q = u & 31;
    int node = min(n0 + r, N_NODES - 1);
    float4 f = *(const float4*)(S + (size_t)node * 128 + q * 4);
    ushort4 o;
    o.x = f2bf(f.x); o.y = f2bf(f.y); o.z = f2bf(f.z); o.w = f2bf(f.w);
    *(ushort4*)(&A[r * PU + 64 + q * 4]) = o;
  }
  __syncthreads();

  const int wid = tid >> 6, lane = tid & 63;
  const int lrow = lane & 15, lk = lane >> 4;
  const int r0 = wid * 16;

  // GEMM1: (64x192) @ (192x128)  [weight rows 64..191 = W2u]
  f32x4 acc[8] = {};
  const uint16_t* Abase = &A[(r0 + lrow) * PU + lk * 8];
  #pragma unroll
  for (int c = 0; c < 6; ++c) {
    short8 a = *(const short8*)(Abase + c * 32);
    #pragma unroll
    for (int n = 0; n < 8; ++n) {
      short8 b = *(const short8*)(Wu1p + ((size_t)((c * 128) + (n * 16 + lrow)) * 4 + lk) * 8);
      acc[n] = __builtin_amdgcn_mfma_f32_16x16x32_bf16(a, b, acc[n], 0, 0, 0);
    }
  }

  // bias + cnt*q + LN + SiLU -> Hs (strip overlay on A)
  uint16_t* strip = &A[r0 * PU];
  #pragma unroll
  for (int reg = 0; reg < 4; ++reg) {
    float cf = scnt[r0 + lk * 4 + reg];
    float v[8];
    float s = 0.f, ss = 0.f;
    #pragma unroll
    for (int n = 0; n < 8; ++n) {
      int col = n * 16 + lrow;
      v[n] = acc[n][reg] + sb1[col] + cf * sq[col];
      s += v[n]; ss += v[n] * v[n];
    }
    #pragma unroll
    for (int m = 1; m <= 8; m <<= 1) {
      s += __shfl_xor(s, m);
      ss += __shfl_xor(ss, m);
    }
    float mu = s * (1.f / 128.f);
    float rstd = rsqrtf(ss * (1.f / 128.f) - mu * mu + LN_EPS);
    uint16_t* hrow = strip + (lk * 4 + reg) * PH;
    #pragma unroll
    for (int n = 0; n < 8; ++n) {
      int col = n * 16 + lrow;
      float h = (v[n] - mu) * rstd * sg[col] + sbe[col];
      h = h / (1.f + __expf(-h));
      hrow[col] = f2bf(h);
    }
  }

  // GEMM2: (64x128) @ (128x64)
  f32x4 acc2[4] = {};
  const uint16_t* Hbase = strip + lrow * PH + lk * 8;
  #pragma unroll
  for (int c = 0; c < 4; ++c) {
    short8 a = *(const short8*)(Hbase + c * 32);
    #pragma unroll
    for (int n = 0; n < 4; ++n) {
      short8 b = *(const short8*)(Wu2p + ((size_t)((c * 64) + (n * 16 + lrow)) * 4 + lk) * 8);
      acc2[n] = __builtin_amdgcn_mfma_f32_16x16x32_bf16(a, b, acc2[n], 0, 0, 0);
    }
  }

  // residual + bias + store f32
  #pragma unroll
  for (int reg = 0; reg < 4; ++reg) {
    int node = n0 + r0 + lk * 4 + reg;
    if (node < N_NODES) {
      #pragma unroll
      for (int n = 0; n < 4; ++n) {
        int col = n * 16 + lrow;
        out[(size_t)node * 64 + col] =
            x[(size_t)node * 64 + col] + acc2[n][reg] + sb2[col];
      }
    }
  }
}

extern "C" void kernel_launch(void* const* d_in, const int* in_sizes, int n_in,
                              void* d_out, int out_size, void* d_ws, size_t ws_size,
                              hipStream_t stream) {
  const float* x   = (const float*)d_in[0];
  const int*   ei  = (const int*)d_in[1];
  const float* ea  = (const float*)d_in[2];
  const float* W1  = (const float*)d_in[3];
  const float* b1  = (const float*)d_in[4];
  const float* g1  = (const float*)d_in[5];
  const float* be1 = (const float*)d_in[6];
  const float* W2  = (const float*)d_in[7];
  const float* b2  = (const float*)d_in[8];
  const float* Wu1 = (const float*)d_in[9];
  const float* bu1 = (const float*)d_in[10];
  const float* gu  = (const float*)d_in[11];
  const float* beu = (const float*)d_in[12];
  const float* Wu2 = (const float*)d_in[13];
  const float* bu2 = (const float*)d_in[14];
  float* out = (float*)d_out;

  char* ws = (char*)d_ws;
  float*    S      = (float*)ws;                        // 51,200,000
  uint16_t* P12    = (uint16_t*)(ws + 51200000);        // 51,200,000
  uint16_t* Wcatp  = (uint16_t*)(ws + 102400000);       // 32,768
  uint16_t* Wu1p   = (uint16_t*)(ws + 102432768);       // 49,152
  uint16_t* Wu2p   = (uint16_t*)(ws + 102481920);       // 16,384
  uint16_t* W1cb   = (uint16_t*)(ws + 102498304);       // 8,192
  float*    qv     = (float*)(ws + 102506496);          // 512
  int*      cnt    = (int*)(ws + 102507008);            // 400,000
  int*      offs   = (int*)(ws + 102907008);            // 400,000
  int*      cursor = (int*)(ws + 103307008);            // 400,000
  int*      bsum   = (int*)(ws + 103707008);            // 512
  int2*     se_s   = (int2*)(ws + 103707520);           // 6,400,000
  int*      dst_s  = (int*)(ws + 110107520);            // 3,200,000 (end ~113.3 MB)

  (void)hipMemsetAsync(cnt, 0, (size_t)N_NODES * 4, stream);

  prep_kernel<<<PREP_HIST_BLKS + PREP_PACK_BLKS, 256, 0, stream>>>(
      ei, cnt, W1, Wcatp, W1cb, Wu1, Wu1p, Wu2, Wu2p, W2, b2, qv);

  scan_blk<<<NB_SCAN, 256, 0, stream>>>(cnt, offs, bsum);
  scan_top<<<1, 128, 0, stream>>>(bsum);
  scan_add<<<(N_NODES + 255) / 256, 256, 0, stream>>>(offs, bsum, cursor);
  scatter_edges<<<SCAT_BLKS + SZERO_BLKS, 256, 0, stream>>>(ei, cursor, se_s, dst_s, S);

  p12_kernel<<<(N_NODES + 63) / 64, 256, 0, stream>>>(x, Wcatp, P12);

  msg_fused<<<N_EDGES / 64, 256, 0, stream>>>(se_s, dst_s, ea, P12,
                                              W1cb, b1, g1, be1, S);

  upd_kernel<<<(N_NODES + 63) / 64, 256, 0, stream>>>(x, S, cnt, qv,
                                                      Wu1p, bu1, gu, beu, Wu2p, bu2, out);
}